// Round 9
// baseline (180.596 us; speedup 1.0000x reference)
//
#include <hip/hip_runtime.h>
#include <math.h>

#define B_    4
#define L_    4096
#define DM    128
#define DI    256
#define DS    16
#define DTR   8
#define XPN   (DTR + 2*DS)   // 40
#define NB    (DI + 2*DS)    // 288 fused xproj output cols
#define M_    (B_*L_)        // 16384
#define CHUNK 32
#define NC    (L_/CHUNK)     // 128
#define LOG2E 1.4426950408889634f
#define PREPW_N (512*128 + NB*DI + DM*DI)   // 172032

typedef __attribute__((ext_vector_type(8))) short bf16x8;   // 8 bf16 = 4 VGPR
typedef __attribute__((ext_vector_type(4))) float f32x4;    // MFMA acc
typedef unsigned short ushort_t;
typedef unsigned int uint_t;

__device__ __forceinline__ ushort_t f2bf(float f) {  // fp32 -> bf16 RNE
  unsigned int u = __float_as_uint(f);
  u += 0x7FFFu + ((u >> 16) & 1u);
  return (ushort_t)(u >> 16);
}
__device__ __forceinline__ float bf2f(ushort_t u) {
  return __uint_as_float(((unsigned int)u) << 16);
}
__device__ __forceinline__ uint_t pack2(float p, float s) {
  return (uint_t)f2bf(p) | ((uint_t)f2bf(s) << 16);
}

// ---------------- prep: weights -> bf16 transposed [N][K]; dtproj folded ----
__global__ __launch_bounds__(256) void prep_w_kernel(const float* __restrict__ inW,
                                                     const float* __restrict__ Wx,
                                                     const float* __restrict__ Wdt,
                                                     const float* __restrict__ outw,
                                                     ushort_t* __restrict__ inWt,
                                                     ushort_t* __restrict__ WbigT,
                                                     ushort_t* __restrict__ outWt) {
  int g = blockIdx.x * 256 + threadIdx.x;
  if (g < 512 * 128) {
    int n = g >> 7, k = g & 127;
    inWt[g] = f2bf(inW[k * 512 + n]);
  } else if (g < 512 * 128 + NB * DI) {
    int q = g - 512 * 128;
    int c = q >> 8, k = q & 255;
    float v;
    if (c < DI) {
      v = 0.f;
      #pragma unroll
      for (int j = 0; j < DTR; ++j) v = fmaf(Wx[k * XPN + j], Wdt[j * DI + c], v);
    } else {
      v = Wx[k * XPN + DTR + (c - DI)];
    }
    WbigT[q] = f2bf(v);
  } else if (g < PREPW_N) {
    int q = g - (512 * 128 + NB * DI);
    int n = q >> 8, k = q & 255;
    outWt[q] = f2bf(outw[k * DM + n]);
  }
}

// ---------------- G1 fused: rmsnorm + in_proj MFMA + depthwise conv + SiLU ---
// A staged from fp32 x with rms*norm_w folded. Col-tiles by<4 -> xi (conv+silu
// -> xcbf); by>=4 -> res (-> resbf). Boundary rows via extra 16-row MFMA tile.
__global__ __launch_bounds__(256) void g1_conv_kernel(const float* __restrict__ x,
                                                      const float* __restrict__ nw,
                                                      const ushort_t* __restrict__ Wt,
                                                      const float* __restrict__ cw,
                                                      const float* __restrict__ cb,
                                                      ushort_t* __restrict__ xcbf,
                                                      ushort_t* __restrict__ resbf) {
  constexpr int NT = 4;  // BN=64
  __shared__ __align__(16) char smem_raw[46528];
  ushort_t (*Asm)[145][8] = (ushort_t (*)[145][8])smem_raw;            // 16 kb: 37120 B
  ushort_t (*Bsm)[65][8]  = (ushort_t (*)[65][8])(smem_raw + 37120);   // 8320 B
  float* scl = (float*)(smem_raw + 45440);                             // 144 floats
  float* nwS = (float*)(smem_raw + 46016);                             // 128 floats
  float* T   = (float*)smem_raw;                                       // [131][68] fp32 (post-MFMA)
  const int tid  = threadIdx.x;
  const int wave = tid >> 6, lane = tid & 63;
  const int quad = lane >> 4, l16 = lane & 15;
  const int row0 = blockIdx.x * 128;
  const int by   = blockIdx.y;
  const int col0 = by * 64;
  const bool zpad = (row0 & (L_ - 1)) == 0;  // batch start: rows <row0 are 0

  if (tid < 32) ((float4*)nwS)[tid] = ((const float4*)nw)[tid];
  // ---- phase a: per-row rms scales (144 rows, wave-pair reduction) ----
  for (int i = 0; i < 18; ++i) {
    int p = wave * 18 + i;
    int m = 2 * p + (lane >> 5);
    float4 v = make_float4(0.f, 0.f, 0.f, 0.f);
    if (!(zpad && m < 16))
      v = *(const float4*)(x + (size_t)(row0 - 16 + m) * DM + (lane & 31) * 4);
    float s = v.x * v.x + v.y * v.y + v.z * v.z + v.w * v.w;
    #pragma unroll
    for (int off = 16; off > 0; off >>= 1) s += __shfl_xor(s, off);
    if ((lane & 31) == 0) scl[m] = rsqrtf(s / DM + 1e-5f);
  }
  __syncthreads();

  // ---- phase b: stage A (144 x 128) bf16 with rms*nw fold ----
  #pragma unroll
  for (int i = 0; i < 9; ++i) {  // 2304 = 9*256
    int q = tid + i * 256;
    int m = q >> 4, kb = q & 15;
    bf16x8 v8 = {0, 0, 0, 0, 0, 0, 0, 0};
    if (!(zpad && m < 16)) {
      const float* xp = x + (size_t)(row0 - 16 + m) * DM + kb * 8;
      float4 a = ((const float4*)xp)[0], b = ((const float4*)xp)[1];
      float sc = scl[m];
      float4 n0 = *(const float4*)(nwS + kb * 8);
      float4 n1 = *(const float4*)(nwS + kb * 8 + 4);
      v8[0] = (short)f2bf(a.x * sc * n0.x); v8[1] = (short)f2bf(a.y * sc * n0.y);
      v8[2] = (short)f2bf(a.z * sc * n0.z); v8[3] = (short)f2bf(a.w * sc * n0.w);
      v8[4] = (short)f2bf(b.x * sc * n1.x); v8[5] = (short)f2bf(b.y * sc * n1.y);
      v8[6] = (short)f2bf(b.z * sc * n1.z); v8[7] = (short)f2bf(b.w * sc * n1.w);
    }
    *(bf16x8*)(&Asm[kb][m][0]) = v8;
  }

  f32x4 acc[2][NT], acc2[NT];
  #pragma unroll
  for (int mt = 0; mt < 2; ++mt)
    #pragma unroll
    for (int nt = 0; nt < NT; ++nt) acc[mt][nt] = (f32x4){0.f, 0.f, 0.f, 0.f};
  #pragma unroll
  for (int nt = 0; nt < NT; ++nt) acc2[nt] = (f32x4){0.f, 0.f, 0.f, 0.f};

  #pragma unroll
  for (int k0i = 0; k0i < 2; ++k0i) {
    #pragma unroll
    for (int i = 0; i < 2; ++i) {  // B: 64x64 bf16
      int q = tid + i * 256;
      int n = q >> 3, kb = q & 7;
      *(bf16x8*)(&Bsm[kb][n][0]) =
          *(const bf16x8*)(Wt + (size_t)(col0 + n) * DM + k0i * 64 + kb * 8);
    }
    __syncthreads();
    #pragma unroll
    for (int ks = 0; ks < 2; ++ks) {
      int kbg = k0i * 8 + ks * 4 + quad;
      bf16x8 af[2], bfr[NT];
      #pragma unroll
      for (int mt = 0; mt < 2; ++mt)
        af[mt] = *(const bf16x8*)(&Asm[kbg][16 + wave * 32 + mt * 16 + l16][0]);
      #pragma unroll
      for (int nt = 0; nt < NT; ++nt)
        bfr[nt] = *(const bf16x8*)(&Bsm[ks * 4 + quad][nt * 16 + l16][0]);
      #pragma unroll
      for (int mt = 0; mt < 2; ++mt)
        #pragma unroll
        for (int nt = 0; nt < NT; ++nt)
          acc[mt][nt] = __builtin_amdgcn_mfma_f32_16x16x32_bf16(af[mt], bfr[nt],
                                                                acc[mt][nt], 0, 0, 0);
      if (by < 4 && wave == 0) {
        bf16x8 ab = *(const bf16x8*)(&Asm[kbg][l16][0]);
        #pragma unroll
        for (int nt = 0; nt < NT; ++nt)
          acc2[nt] = __builtin_amdgcn_mfma_f32_16x16x32_bf16(ab, bfr[nt],
                                                             acc2[nt], 0, 0, 0);
      }
    }
    __syncthreads();
  }

  if (by < 4) {
    #pragma unroll
    for (int mt = 0; mt < 2; ++mt)
      #pragma unroll
      for (int nt = 0; nt < NT; ++nt)
        #pragma unroll
        for (int r = 0; r < 4; ++r)
          T[(3 + wave * 32 + mt * 16 + quad * 4 + r) * 68 + nt * 16 + l16] =
              acc[mt][nt][r];
    if (wave == 0 && quad == 3) {
      #pragma unroll
      for (int nt = 0; nt < NT; ++nt)
        #pragma unroll
        for (int r = 1; r < 4; ++r)  // boundary rows 13,14,15 -> T[0..2]
          T[(r - 1) * 68 + nt * 16 + l16] = acc2[nt][r];
    }
    __syncthreads();
    const int c   = tid & 63;
    const int R0  = (tid >> 6) * 32;
    const int dch = col0 + c;
    float4 w4   = *(const float4*)(cw + dch * 4);
    float bias  = cb[dch];
    float t0 = T[(R0 + 0) * 68 + c];
    float t1 = T[(R0 + 1) * 68 + c];
    float t2 = T[(R0 + 2) * 68 + c];
    for (int rr = 0; rr < 32; ++rr) {
      float t3 = T[(R0 + rr + 3) * 68 + c];
      float s = fmaf(w4.x, t0, fmaf(w4.y, t1, fmaf(w4.z, t2, fmaf(w4.w, t3, bias))));
      float v = s / (1.f + __expf(-s));
      xcbf[(size_t)(row0 + R0 + rr) * DI + dch] = f2bf(v);
      t0 = t1; t1 = t2; t2 = t3;
    }
  } else {
    const int cr = col0 - 256;
    #pragma unroll
    for (int mt = 0; mt < 2; ++mt)
      #pragma unroll
      for (int nt = 0; nt < NT; ++nt) {
        int col   = cr + nt * 16 + l16;
        int rbase = row0 + wave * 32 + mt * 16 + quad * 4;
        #pragma unroll
        for (int r = 0; r < 4; ++r)
          resbf[(size_t)(rbase + r) * DI + col] = f2bf(acc[mt][nt][r]);
      }
  }
}

// ---------------- scanA fused: xproj MFMA (LDS) + phase-A chunk scan --------
// One block per (b, chunk). Emits delta/Bm/Cm (bf16) + packed bf16 (P,S).
__global__ __launch_bounds__(512, 4) void scanA_kernel(
    const ushort_t* __restrict__ xcbf, const ushort_t* __restrict__ WbigT,
    const float* __restrict__ bdt, const float* __restrict__ Alog,
    ushort_t* __restrict__ deltab, ushort_t* __restrict__ Bmb,
    ushort_t* __restrict__ Cmb, uint_t* __restrict__ PS) {
  __shared__ __align__(16) ushort_t Asm[32][33][8];  // xc tile 16.9 KB
  __shared__ float T[32][257];                       // delta fp32 32.9 KB
  __shared__ float Bs[32][17], Cs[32][17];
  const int tid  = threadIdx.x;
  const int wave = tid >> 6, lane = tid & 63;
  const int quad = lane >> 4, l16 = lane & 15;
  const int b = blockIdx.x >> 7, c = blockIdx.x & (NC - 1);
  const size_t rowbase = (size_t)b * L_ + (size_t)c * CHUNK;
  const int d  = (wave << 5) | (lane & 31);
  const int nh = lane >> 5;
  const int n0 = nh * 8;

  {  // stage xc chunk tile (32 rows x 256 ch)
    int m = tid & 31, kb = tid >> 5;
    *(bf16x8*)(&Asm[kb][m][0]) =
        *(const bf16x8*)(xcbf + (rowbase + m) * DI + kb * 8);
    *(bf16x8*)(&Asm[kb + 16][m][0]) =
        *(const bf16x8*)(xcbf + (rowbase + m) * DI + (kb + 16) * 8);
  }
  __syncthreads();

  // xproj: 2 m-tiles x 18 n-tiles, K=256, B-frags streamed from L2
  for (int tp = wave; tp < 36; tp += 8) {
    int mt = tp / 18, nt = tp % 18;
    f32x4 acc = {0.f, 0.f, 0.f, 0.f};
    #pragma unroll
    for (int ks = 0; ks < 8; ++ks) {
      bf16x8 af = *(const bf16x8*)(&Asm[ks * 4 + quad][mt * 16 + l16][0]);
      bf16x8 bf = *(const bf16x8*)(WbigT + (size_t)(nt * 16 + l16) * DI + ks * 32 + quad * 8);
      acc = __builtin_amdgcn_mfma_f32_16x16x32_bf16(af, bf, acc, 0, 0, 0);
    }
    int row = mt * 16 + quad * 4;
    if (nt < 16) {
      int col = nt * 16 + l16;
      float bb = bdt[col];
      #pragma unroll
      for (int r = 0; r < 4; ++r) {
        float v = acc[r] + bb;
        T[row + r][col] = (v > 20.f) ? v : log1pf(__expf(v));  // softplus
      }
    } else if (nt == 16) {
      #pragma unroll
      for (int r = 0; r < 4; ++r) Bs[row + r][l16] = acc[r];
    } else {
      #pragma unroll
      for (int r = 0; r < 4; ++r) Cs[row + r][l16] = acc[r];
    }
  }
  __syncthreads();

  // export delta (packed) + B/C bf16 for scanC
  #pragma unroll
  for (int i = 0; i < 8; ++i) {
    int idx2 = tid + i * 512;
    int row = idx2 >> 7, cp = idx2 & 127;
    unsigned int pk = (unsigned int)f2bf(T[row][2 * cp]) |
                      ((unsigned int)f2bf(T[row][2 * cp + 1]) << 16);
    *(unsigned int*)(deltab + (rowbase + row) * DI + 2 * cp) = pk;
  }
  {
    int row = tid >> 4, n = tid & 15;
    Bmb[rowbase * DS + tid] = f2bf(Bs[row][n]);
    Cmb[rowbase * DS + tid] = f2bf(Cs[row][n]);
  }

  float c0 = -__expf(Alog[d * DS]) * LOG2E;
  float aln[8];
  #pragma unroll
  for (int j = 0; j < 8; ++j) aln[j] = -__expf(Alog[d * DS + n0 + j]) * LOG2E;
  bool geom = true;
  #pragma unroll
  for (int j = 0; j < 8; ++j)
    geom = geom && (fabsf(aln[j] - (n0 + j + 1) * c0) <= 1e-3f * fabsf(aln[j]));

  float P[8], S[8];
  #pragma unroll
  for (int j = 0; j < 8; ++j) { P[j] = 1.f; S[j] = 0.f; }
  for (int t = 0; t < CHUNK; ++t) {
    float dl = T[t][d];
    float xv = bf2f(Asm[d >> 3][t][d & 7]);
    float du = dl * xv;
    if (geom) {
      float e1 = exp2f(dl * c0);
      float a;
      if (nh) { float e2 = e1 * e1, e4 = e2 * e2; a = e4 * e4 * e1; }  // e1^9
      else a = e1;
      #pragma unroll
      for (int j = 0; j < 8; ++j) {
        P[j] *= a;
        S[j] = fmaf(a, S[j], du * Bs[t][n0 + j]);
        a *= e1;
      }
    } else {
      #pragma unroll
      for (int j = 0; j < 8; ++j) {
        float a = exp2f(dl * aln[j]);
        P[j] *= a;
        S[j] = fmaf(a, S[j], du * Bs[t][n0 + j]);
      }
    }
  }
  size_t ob = ((size_t)(b * NC + c) << 12) + ((nh * 256 + d) << 3);
  uint4 w0, w1;
  w0.x = pack2(P[0], S[0]); w0.y = pack2(P[1], S[1]);
  w0.z = pack2(P[2], S[2]); w0.w = pack2(P[3], S[3]);
  w1.x = pack2(P[4], S[4]); w1.y = pack2(P[5], S[5]);
  w1.z = pack2(P[6], S[6]); w1.w = pack2(P[7], S[7]);
  *(uint4*)(PS + ob)     = w0;
  *(uint4*)(PS + ob + 4) = w1;
}

// ---------------- scan phase B: scan over chunk summaries ----------------
__global__ __launch_bounds__(64) void scanB_kernel(const uint_t* __restrict__ PS,
                                                   float* __restrict__ sinit) {
  int g  = blockIdx.x * 64 + threadIdx.x;
  int b  = g >> 12;
  int dn = g & 4095;
  float s = 0.f;
  #pragma unroll 16
  for (int c = 0; c < NC; ++c) {
    size_t idx = ((size_t)(b * NC + c) << 12) + dn;
    sinit[idx] = s;
    uint_t v = PS[idx];
    s = fmaf(bf2f((ushort_t)(v & 0xffffu)), s, bf2f((ushort_t)(v >> 16)));
  }
}

// ---------------- scanC fused: replay + gated y2 + out_proj MFMA + residual --
__global__ __launch_bounds__(512, 4) void scanC_kernel(
    const ushort_t* __restrict__ deltab, const ushort_t* __restrict__ xcbf,
    const ushort_t* __restrict__ Bmb, const ushort_t* __restrict__ Cmb,
    const float* __restrict__ Alog, const float* __restrict__ Dp,
    const ushort_t* __restrict__ resbf, const float* __restrict__ sinit,
    const ushort_t* __restrict__ outWt, const float* __restrict__ x,
    float* __restrict__ out) {
  __shared__ float Bs[32][17], Cs[32][17];
  __shared__ __align__(16) ushort_t y2s[32][264];  // 16.9 KB
  const int tid  = threadIdx.x;
  const int wave = tid >> 6, lane = tid & 63;
  const int quad = lane >> 4, l16 = lane & 15;
  const int b = blockIdx.x >> 7, c = blockIdx.x & (NC - 1);
  const size_t rowbase = (size_t)b * L_ + (size_t)c * CHUNK;
  const int d  = (wave << 5) | (lane & 31);
  const int nh = lane >> 5;
  const int n0 = nh * 8;
  {
    int row = tid >> 4, n = tid & 15;
    Bs[row][n] = bf2f(Bmb[rowbase * DS + tid]);
    Cs[row][n] = bf2f(Cmb[rowbase * DS + tid]);
  }
  float c0 = -__expf(Alog[d * DS]) * LOG2E;
  float aln[8];
  #pragma unroll
  for (int j = 0; j < 8; ++j) aln[j] = -__expf(Alog[d * DS + n0 + j]) * LOG2E;
  bool geom = true;
  #pragma unroll
  for (int j = 0; j < 8; ++j)
    geom = geom && (fabsf(aln[j] - (n0 + j + 1) * c0) <= 1e-3f * fabsf(aln[j]));
  const float Dd = Dp[d];
  float S[8];
  {
    size_t ib = ((size_t)(b * NC + c) << 12) + ((nh * 256 + d) << 3);
    float4 v0 = *(const float4*)(sinit + ib);
    float4 v1 = *(const float4*)(sinit + ib + 4);
    S[0] = v0.x; S[1] = v0.y; S[2] = v0.z; S[3] = v0.w;
    S[4] = v1.x; S[5] = v1.y; S[6] = v1.z; S[7] = v1.w;
  }
  __syncthreads();
  for (int t = 0; t < CHUNK; ++t) {
    float dl = bf2f(deltab[(rowbase + t) * DI + d]);
    float xv = bf2f(xcbf[(rowbase + t) * DI + d]);
    float du = dl * xv;
    float y = 0.f;
    if (geom) {
      float e1 = exp2f(dl * c0);
      float a;
      if (nh) { float e2 = e1 * e1, e4 = e2 * e2; a = e4 * e4 * e1; }
      else a = e1;
      #pragma unroll
      for (int j = 0; j < 8; ++j) {
        S[j] = fmaf(a, S[j], du * Bs[t][n0 + j]);
        y = fmaf(S[j], Cs[t][n0 + j], y);
        a *= e1;
      }
    } else {
      #pragma unroll
      for (int j = 0; j < 8; ++j) {
        float a = exp2f(dl * aln[j]);
        S[j] = fmaf(a, S[j], du * Bs[t][n0 + j]);
        y = fmaf(S[j], Cs[t][n0 + j], y);
      }
    }
    float yo = __shfl_xor(y, 32);
    if (nh == 0) {
      float rv = bf2f(resbf[(rowbase + t) * DI + d]);
      float yt = y + yo + xv * Dd;
      float sil = rv / (1.f + __expf(-rv));
      y2s[t][d] = f2bf(yt * sil);
    }
  }
  __syncthreads();
  // out_proj: 32x256 (LDS) @ outWt[128][256]^T + x -> out 32x128
  #pragma unroll
  for (int mt = 0; mt < 2; ++mt) {
    f32x4 acc = {0.f, 0.f, 0.f, 0.f};
    #pragma unroll
    for (int ks = 0; ks < 8; ++ks) {
      bf16x8 af = *(const bf16x8*)(&y2s[mt * 16 + l16][ks * 32 + quad * 8]);
      bf16x8 bf = *(const bf16x8*)(outWt + (size_t)(wave * 16 + l16) * DI + ks * 32 + quad * 8);
      acc = __builtin_amdgcn_mfma_f32_16x16x32_bf16(af, bf, acc, 0, 0, 0);
    }
    int col = wave * 16 + l16;
    size_t rb = rowbase + mt * 16 + quad * 4;
    #pragma unroll
    for (int r = 0; r < 4; ++r)
      out[(rb + r) * DM + col] = acc[r] + x[(rb + r) * DM + col];
  }
}

extern "C" void kernel_launch(void* const* d_in, const int* in_sizes, int n_in,
                              void* d_out, int out_size, void* d_ws, size_t ws_size,
                              hipStream_t stream) {
  const float* x      = (const float*)d_in[0];
  const float* norm_w = (const float*)d_in[1];
  const float* inW    = (const float*)d_in[2];
  const float* convw  = (const float*)d_in[3];
  const float* convb  = (const float*)d_in[4];
  const float* xprojw = (const float*)d_in[5];
  const float* dtw    = (const float*)d_in[6];
  const float* dtb    = (const float*)d_in[7];
  const float* alog   = (const float*)d_in[8];
  const float* Dp     = (const float*)d_in[9];
  const float* outw   = (const float*)d_in[10];
  float* out = (float*)d_out;

  const size_t CS = (size_t)B_ * NC * DI * DS;  // 2,097,152
  uint_t* PS    = (uint_t*)d_ws;                 // CS uints (8 MB)
  float* sinit  = (float*)(PS + CS);             // CS floats (8 MB)
  ushort_t* bfbase = (ushort_t*)(sinit + CS);
  ushort_t* xcbf   = bfbase;                        // M_*256
  ushort_t* resbf  = xcbf + (size_t)M_ * DI;        // M_*256
  ushort_t* deltab = resbf + (size_t)M_ * DI;       // M_*256
  ushort_t* Bmb    = deltab + (size_t)M_ * DI;      // M_*16
  ushort_t* Cmb    = Bmb + (size_t)M_ * DS;         // M_*16
  ushort_t* inWt   = Cmb + (size_t)M_ * DS;         // 512*128
  ushort_t* WbigT  = inWt + 512 * 128;              // 288*256
  ushort_t* outWt  = WbigT + NB * DI;               // 128*256

  prep_w_kernel<<<(PREPW_N + 255) / 256, 256, 0, stream>>>(
      inW, xprojw, dtw, outw, inWt, WbigT, outWt);
  g1_conv_kernel<<<dim3(M_ / 128, 8), 256, 0, stream>>>(
      x, norm_w, inWt, convw, convb, xcbf, resbf);
  scanA_kernel<<<B_ * NC, 512, 0, stream>>>(
      xcbf, WbigT, dtb, alog, deltab, Bmb, Cmb, PS);
  scanB_kernel<<<(B_ * DI * DS) / 64, 64, 0, stream>>>(PS, sinit);
  scanC_kernel<<<B_ * NC, 512, 0, stream>>>(
      deltab, xcbf, Bmb, Cmb, alog, Dp, resbf, sinit, outWt, x, out);
}

// Round 10
// 169.008 us; speedup vs baseline: 1.0686x; 1.0686x over previous
//
#include <hip/hip_runtime.h>
#include <math.h>

#define B_    4
#define L_    4096
#define DM    128
#define DI    256
#define DS    16
#define DTR   8
#define XPN   (DTR + 2*DS)   // 40
#define NB    (DI + 2*DS)    // 288 fused xproj output cols
#define M_    (B_*L_)        // 16384
#define CHUNK 32
#define NC    (L_/CHUNK)     // 128
#define LOG2E 1.4426950408889634f
#define PREP_N (512*128 + NB*DI + DM*DI)   // 172032

typedef __attribute__((ext_vector_type(8))) short bf16x8;   // 8 bf16 = 4 VGPR
typedef __attribute__((ext_vector_type(4))) float f32x4;    // MFMA acc
typedef unsigned short ushort_t;

__device__ __forceinline__ ushort_t f2bf(float f) {  // fp32 -> bf16 RNE
  unsigned int u = __float_as_uint(f);
  u += 0x7FFFu + ((u >> 16) & 1u);
  return (ushort_t)(u >> 16);
}
__device__ __forceinline__ float bf2f(ushort_t u) {
  return __uint_as_float(((unsigned int)u) << 16);
}

// ---------------- prep (weights->bf16 transposed, dtproj folded) + rmsnorm ----
__global__ __launch_bounds__(256) void prep_rms_kernel(const float* __restrict__ x,
                                                       const float* __restrict__ nw,
                                                       const float* __restrict__ inW,
                                                       const float* __restrict__ Wx,
                                                       const float* __restrict__ Wdt,
                                                       const float* __restrict__ outw,
                                                       ushort_t* __restrict__ xbf,
                                                       ushort_t* __restrict__ inWt,
                                                       ushort_t* __restrict__ WbigT,
                                                       ushort_t* __restrict__ outWt) {
  if (blockIdx.x < M_ / 4) {  // rmsnorm -> bf16
    int row  = blockIdx.x * 4 + (threadIdx.x >> 6);
    int lane = threadIdx.x & 63;
    const float* xp = x + (size_t)row * DM;
    float v0 = xp[lane], v1 = xp[lane + 64];
    float s = v0 * v0 + v1 * v1;
    #pragma unroll
    for (int off = 32; off > 0; off >>= 1) s += __shfl_xor(s, off);
    float r = rsqrtf(s / DM + 1e-5f);
    ushort_t* op = xbf + (size_t)row * DM;
    op[lane]      = f2bf(v0 * r * nw[lane]);
    op[lane + 64] = f2bf(v1 * r * nw[lane + 64]);
    return;
  }
  int g = (blockIdx.x - M_ / 4) * 256 + threadIdx.x;
  if (g < 512 * 128) {
    int n = g >> 7, k = g & 127;
    inWt[g] = f2bf(inW[k * 512 + n]);
  } else if (g < 512 * 128 + NB * DI) {
    int q = g - 512 * 128;
    int c = q >> 8, k = q & 255;
    float v;
    if (c < DI) {
      v = 0.f;
      #pragma unroll
      for (int j = 0; j < DTR; ++j) v = fmaf(Wx[k * XPN + j], Wdt[j * DI + c], v);
    } else {
      v = Wx[k * XPN + DTR + (c - DI)];
    }
    WbigT[q] = f2bf(v);
  } else if (g < PREP_N) {
    int q = g - (512 * 128 + NB * DI);
    int n = q >> 8, k = q & 255;
    outWt[q] = f2bf(outw[k * DM + n]);
  }
}

// ---------------- G1 fused: in_proj MFMA + depthwise conv + SiLU -------------
// Each block: one staged A-tile (144x128 w/ boundary rows), TWO column tiles:
// xi cols [by*64,+64) -> conv+silu -> xcbf; res cols [256+by*64,+64) -> resbf.
__global__ __launch_bounds__(256) void g1_conv_kernel(const ushort_t* __restrict__ A,
                                                      const ushort_t* __restrict__ Wt,
                                                      const float* __restrict__ cw,
                                                      const float* __restrict__ cb,
                                                      ushort_t* __restrict__ xcbf,
                                                      ushort_t* __restrict__ resbf) {
  constexpr int KK = 128, NT = 4;
  __shared__ __align__(16) char smem_raw[35648];
  ushort_t (*Asm)[145][8] = (ushort_t (*)[145][8])smem_raw;          // 18560 B
  ushort_t (*Bx)[65][8]   = (ushort_t (*)[65][8])(smem_raw + 18560); //  8320 B
  ushort_t (*Br)[65][8]   = (ushort_t (*)[65][8])(smem_raw + 26880); //  8320 B
  float* T = (float*)smem_raw;                                       // [131][68]
  const int tid  = threadIdx.x;
  const int wave = tid >> 6, lane = tid & 63;
  const int quad = lane >> 4, l16 = lane & 15;
  const int row0 = blockIdx.x * 128;
  const int by   = blockIdx.y;          // 0..3
  const int c0x  = by * 64;             // xi cols
  const int c0r  = 256 + by * 64;       // res cols (global N index)
  const bool zpad = (row0 & (L_ - 1)) == 0;
  f32x4 ax[2][NT], ar[2][NT], acc2[NT];
  #pragma unroll
  for (int mt = 0; mt < 2; ++mt)
    #pragma unroll
    for (int nt = 0; nt < NT; ++nt) {
      ax[mt][nt] = (f32x4){0.f, 0.f, 0.f, 0.f};
      ar[mt][nt] = (f32x4){0.f, 0.f, 0.f, 0.f};
    }
  #pragma unroll
  for (int nt = 0; nt < NT; ++nt) acc2[nt] = (f32x4){0.f, 0.f, 0.f, 0.f};

  for (int k0 = 0; k0 < KK; k0 += 64) {
    #pragma unroll
    for (int i = 0; i < 5; ++i) {  // A: 144 rows x 64 bf16 = 1152 b128
      int q = tid + i * 256;
      if (i < 4 || tid < 128) {
        int m = q >> 3, kb = q & 7;
        bf16x8 v = {0, 0, 0, 0, 0, 0, 0, 0};
        if (!(zpad && m < 16))
          v = *(const bf16x8*)(A + (size_t)(row0 - 16 + m) * KK + k0 + kb * 8);
        *(bf16x8*)(&Asm[kb][m][0]) = v;
      }
    }
    #pragma unroll
    for (int i = 0; i < 2; ++i) {  // B xi: 64x64 bf16
      int q = tid + i * 256;
      int n = q >> 3, kb = q & 7;
      *(bf16x8*)(&Bx[kb][n][0]) =
          *(const bf16x8*)(Wt + (size_t)(c0x + n) * KK + k0 + kb * 8);
    }
    #pragma unroll
    for (int i = 0; i < 2; ++i) {  // B res: 64x64 bf16
      int q = tid + i * 256;
      int n = q >> 3, kb = q & 7;
      *(bf16x8*)(&Br[kb][n][0]) =
          *(const bf16x8*)(Wt + (size_t)(c0r + n) * KK + k0 + kb * 8);
    }
    __syncthreads();
    #pragma unroll
    for (int ks = 0; ks < 2; ++ks) {
      bf16x8 af[2], bx[NT], br[NT];
      #pragma unroll
      for (int mt = 0; mt < 2; ++mt)
        af[mt] = *(const bf16x8*)(&Asm[ks * 4 + quad][16 + wave * 32 + mt * 16 + l16][0]);
      #pragma unroll
      for (int nt = 0; nt < NT; ++nt) {
        bx[nt] = *(const bf16x8*)(&Bx[ks * 4 + quad][nt * 16 + l16][0]);
        br[nt] = *(const bf16x8*)(&Br[ks * 4 + quad][nt * 16 + l16][0]);
      }
      #pragma unroll
      for (int mt = 0; mt < 2; ++mt)
        #pragma unroll
        for (int nt = 0; nt < NT; ++nt) {
          ax[mt][nt] = __builtin_amdgcn_mfma_f32_16x16x32_bf16(af[mt], bx[nt],
                                                               ax[mt][nt], 0, 0, 0);
          ar[mt][nt] = __builtin_amdgcn_mfma_f32_16x16x32_bf16(af[mt], br[nt],
                                                               ar[mt][nt], 0, 0, 0);
        }
      if (wave == 0) {  // boundary rows row0-16..row0-1 (xi only)
        bf16x8 ab = *(const bf16x8*)(&Asm[ks * 4 + quad][l16][0]);
        #pragma unroll
        for (int nt = 0; nt < NT; ++nt)
          acc2[nt] = __builtin_amdgcn_mfma_f32_16x16x32_bf16(ab, bx[nt],
                                                             acc2[nt], 0, 0, 0);
      }
    }
    __syncthreads();
  }

  // res epilogue (registers only)
  #pragma unroll
  for (int mt = 0; mt < 2; ++mt)
    #pragma unroll
    for (int nt = 0; nt < NT; ++nt) {
      int col   = c0x + nt * 16 + l16;  // res channel index (c0r-256 == c0x)
      int rbase = row0 + wave * 32 + mt * 16 + quad * 4;
      #pragma unroll
      for (int r = 0; r < 4; ++r)
        resbf[(size_t)(rbase + r) * DI + col] = f2bf(ar[mt][nt][r]);
    }

  // xi epilogue via LDS conv tile
  #pragma unroll
  for (int mt = 0; mt < 2; ++mt)
    #pragma unroll
    for (int nt = 0; nt < NT; ++nt)
      #pragma unroll
      for (int r = 0; r < 4; ++r)
        T[(3 + wave * 32 + mt * 16 + quad * 4 + r) * 68 + nt * 16 + l16] =
            ax[mt][nt][r];
  if (wave == 0 && quad == 3) {
    #pragma unroll
    for (int nt = 0; nt < NT; ++nt)
      #pragma unroll
      for (int r = 1; r < 4; ++r)  // boundary rows 13,14,15 -> T[0..2]
        T[(r - 1) * 68 + nt * 16 + l16] = acc2[nt][r];
  }
  __syncthreads();
  {
    const int c   = tid & 63;
    const int R0  = (tid >> 6) * 32;
    const int dch = c0x + c;
    float4 w4   = *(const float4*)(cw + dch * 4);
    float bias  = cb[dch];
    float t0 = T[(R0 + 0) * 68 + c];
    float t1 = T[(R0 + 1) * 68 + c];
    float t2 = T[(R0 + 2) * 68 + c];
    for (int rr = 0; rr < 32; ++rr) {
      float t3 = T[(R0 + rr + 3) * 68 + c];
      float s = fmaf(w4.x, t0, fmaf(w4.y, t1, fmaf(w4.z, t2, fmaf(w4.w, t3, bias))));
      float v = s / (1.f + __expf(-s));
      xcbf[(size_t)(row0 + R0 + rr) * DI + dch] = f2bf(v);
      t0 = t1; t1 = t2; t2 = t3;
    }
  }
}

// ---------------- scanA fused: xproj MFMA (LDS) + phase-A chunk scan --------
// One block per (b, chunk). Emits delta/Bm/Cm (bf16) + (P,S) float2 summaries.
__global__ __launch_bounds__(512, 4) void scanA_kernel(
    const ushort_t* __restrict__ xcbf, const ushort_t* __restrict__ WbigT,
    const float* __restrict__ bdt, const float* __restrict__ Alog,
    ushort_t* __restrict__ deltab, ushort_t* __restrict__ Bmb,
    ushort_t* __restrict__ Cmb, float2* __restrict__ PS) {
  __shared__ __align__(16) ushort_t Asm[32][33][8];  // xc tile 16.9 KB
  __shared__ float T[32][257];                       // delta fp32 32.9 KB
  __shared__ float Bs[32][17], Cs[32][17];
  const int tid  = threadIdx.x;
  const int wave = tid >> 6, lane = tid & 63;
  const int quad = lane >> 4, l16 = lane & 15;
  const int b = blockIdx.x >> 7, c = blockIdx.x & (NC - 1);
  const size_t rowbase = (size_t)b * L_ + (size_t)c * CHUNK;
  const int d  = (wave << 5) | (lane & 31);
  const int nh = lane >> 5;
  const int n0 = nh * 8;

  {  // stage xc chunk tile (32 rows x 256 ch)
    int m = tid & 31, kb = tid >> 5;
    *(bf16x8*)(&Asm[kb][m][0]) =
        *(const bf16x8*)(xcbf + (rowbase + m) * DI + kb * 8);
    *(bf16x8*)(&Asm[kb + 16][m][0]) =
        *(const bf16x8*)(xcbf + (rowbase + m) * DI + (kb + 16) * 8);
  }
  __syncthreads();

  // xproj: 2 m-tiles x 18 n-tiles, K=256, B-frags streamed from L2
  for (int tp = wave; tp < 36; tp += 8) {
    int mt = tp / 18, nt = tp % 18;
    f32x4 acc = {0.f, 0.f, 0.f, 0.f};
    #pragma unroll
    for (int ks = 0; ks < 8; ++ks) {
      bf16x8 af = *(const bf16x8*)(&Asm[ks * 4 + quad][mt * 16 + l16][0]);
      bf16x8 bf = *(const bf16x8*)(WbigT + (size_t)(nt * 16 + l16) * DI + ks * 32 + quad * 8);
      acc = __builtin_amdgcn_mfma_f32_16x16x32_bf16(af, bf, acc, 0, 0, 0);
    }
    int row = mt * 16 + quad * 4;
    if (nt < 16) {
      int col = nt * 16 + l16;
      float bb = bdt[col];
      #pragma unroll
      for (int r = 0; r < 4; ++r) {
        float v = acc[r] + bb;
        T[row + r][col] = (v > 20.f) ? v : log1pf(__expf(v));  // softplus
      }
    } else if (nt == 16) {
      #pragma unroll
      for (int r = 0; r < 4; ++r) Bs[row + r][l16] = acc[r];
    } else {
      #pragma unroll
      for (int r = 0; r < 4; ++r) Cs[row + r][l16] = acc[r];
    }
  }
  __syncthreads();

  // export delta (packed uint) + B/C bf16 for scanC
  #pragma unroll
  for (int i = 0; i < 8; ++i) {
    int idx2 = tid + i * 512;  // 0..4095 col-pairs
    int row = idx2 >> 7, cp = idx2 & 127;
    unsigned int pk = (unsigned int)f2bf(T[row][2 * cp]) |
                      ((unsigned int)f2bf(T[row][2 * cp + 1]) << 16);
    *(unsigned int*)(deltab + (rowbase + row) * DI + 2 * cp) = pk;
  }
  {
    int row = tid >> 4, n = tid & 15;
    Bmb[rowbase * DS + tid] = f2bf(Bs[row][n]);
    Cmb[rowbase * DS + tid] = f2bf(Cs[row][n]);
  }

  float c0 = -__expf(Alog[d * DS]) * LOG2E;
  float aln[8];
  #pragma unroll
  for (int j = 0; j < 8; ++j) aln[j] = -__expf(Alog[d * DS + n0 + j]) * LOG2E;
  bool geom = true;
  #pragma unroll
  for (int j = 0; j < 8; ++j)
    geom = geom && (fabsf(aln[j] - (n0 + j + 1) * c0) <= 1e-3f * fabsf(aln[j]));

  float P[8], S[8];
  #pragma unroll
  for (int j = 0; j < 8; ++j) { P[j] = 1.f; S[j] = 0.f; }
  for (int t = 0; t < CHUNK; ++t) {
    float dl = T[t][d];
    float xv = bf2f(Asm[d >> 3][t][d & 7]);
    float du = dl * xv;
    if (geom) {
      float e1 = exp2f(dl * c0);
      float a;
      if (nh) { float e2 = e1 * e1, e4 = e2 * e2; a = e4 * e4 * e1; }  // e1^9
      else a = e1;
      #pragma unroll
      for (int j = 0; j < 8; ++j) {
        P[j] *= a;
        S[j] = fmaf(a, S[j], du * Bs[t][n0 + j]);
        a *= e1;
      }
    } else {
      #pragma unroll
      for (int j = 0; j < 8; ++j) {
        float a = exp2f(dl * aln[j]);
        P[j] *= a;
        S[j] = fmaf(a, S[j], du * Bs[t][n0 + j]);
      }
    }
  }
  size_t ob = ((size_t)(b * NC + c) << 12) + ((nh * 256 + d) << 3);
  float4* p4 = (float4*)(PS + ob);
  p4[0] = make_float4(P[0], S[0], P[1], S[1]);
  p4[1] = make_float4(P[2], S[2], P[3], S[3]);
  p4[2] = make_float4(P[4], S[4], P[5], S[5]);
  p4[3] = make_float4(P[6], S[6], P[7], S[7]);
}

// ---------------- scan phase B: scan over chunk summaries ----------------
__global__ __launch_bounds__(64) void scanB_kernel(const float2* __restrict__ PS,
                                                   float* __restrict__ sinit) {
  int g  = blockIdx.x * 64 + threadIdx.x;
  int b  = g >> 12;
  int dn = g & 4095;
  float s = 0.f;
  #pragma unroll 16
  for (int c = 0; c < NC; ++c) {
    size_t idx = ((size_t)(b * NC + c) << 12) + dn;
    sinit[idx] = s;
    float2 v = PS[idx];
    s = fmaf(v.x, s, v.y);
  }
}

// ---------------- scanC fused: replay + gated y2 + out_proj MFMA + residual --
__global__ __launch_bounds__(512, 4) void scanC_kernel(
    const ushort_t* __restrict__ deltab, const ushort_t* __restrict__ xcbf,
    const ushort_t* __restrict__ Bmb, const ushort_t* __restrict__ Cmb,
    const float* __restrict__ Alog, const float* __restrict__ Dp,
    const ushort_t* __restrict__ resbf, const float* __restrict__ sinit,
    const ushort_t* __restrict__ outWt, const float* __restrict__ x,
    float* __restrict__ out) {
  __shared__ float Bs[32][17], Cs[32][17];
  __shared__ __align__(16) ushort_t y2s[32][264];  // 16.9 KB
  const int tid  = threadIdx.x;
  const int wave = tid >> 6, lane = tid & 63;
  const int quad = lane >> 4, l16 = lane & 15;
  const int b = blockIdx.x >> 7, c = blockIdx.x & (NC - 1);
  const size_t rowbase = (size_t)b * L_ + (size_t)c * CHUNK;
  const int d  = (wave << 5) | (lane & 31);
  const int nh = lane >> 5;
  const int n0 = nh * 8;
  {
    int row = tid >> 4, n = tid & 15;
    Bs[row][n] = bf2f(Bmb[rowbase * DS + tid]);
    Cs[row][n] = bf2f(Cmb[rowbase * DS + tid]);
  }
  float c0 = -__expf(Alog[d * DS]) * LOG2E;
  float aln[8];
  #pragma unroll
  for (int j = 0; j < 8; ++j) aln[j] = -__expf(Alog[d * DS + n0 + j]) * LOG2E;
  bool geom = true;
  #pragma unroll
  for (int j = 0; j < 8; ++j)
    geom = geom && (fabsf(aln[j] - (n0 + j + 1) * c0) <= 1e-3f * fabsf(aln[j]));
  const float Dd = Dp[d];
  float S[8];
  {
    size_t ib = ((size_t)(b * NC + c) << 12) + ((nh * 256 + d) << 3);
    float4 v0 = *(const float4*)(sinit + ib);
    float4 v1 = *(const float4*)(sinit + ib + 4);
    S[0] = v0.x; S[1] = v0.y; S[2] = v0.z; S[3] = v0.w;
    S[4] = v1.x; S[5] = v1.y; S[6] = v1.z; S[7] = v1.w;
  }
  __syncthreads();
  for (int t = 0; t < CHUNK; ++t) {
    float dl = bf2f(deltab[(rowbase + t) * DI + d]);
    float xv = bf2f(xcbf[(rowbase + t) * DI + d]);
    float du = dl * xv;
    float y = 0.f;
    if (geom) {
      float e1 = exp2f(dl * c0);
      float a;
      if (nh) { float e2 = e1 * e1, e4 = e2 * e2; a = e4 * e4 * e1; }
      else a = e1;
      #pragma unroll
      for (int j = 0; j < 8; ++j) {
        S[j] = fmaf(a, S[j], du * Bs[t][n0 + j]);
        y = fmaf(S[j], Cs[t][n0 + j], y);
        a *= e1;
      }
    } else {
      #pragma unroll
      for (int j = 0; j < 8; ++j) {
        float a = exp2f(dl * aln[j]);
        S[j] = fmaf(a, S[j], du * Bs[t][n0 + j]);
        y = fmaf(S[j], Cs[t][n0 + j], y);
      }
    }
    float yo = __shfl_xor(y, 32);
    if (nh == 0) {
      float rv = bf2f(resbf[(rowbase + t) * DI + d]);
      float yt = y + yo + xv * Dd;
      float sil = rv / (1.f + __expf(-rv));
      y2s[t][d] = f2bf(yt * sil);
    }
  }
  __syncthreads();
  // out_proj: 32x256 (LDS) @ outWt[128][256]^T + x -> out 32x128
  #pragma unroll
  for (int mt = 0; mt < 2; ++mt) {
    f32x4 acc = {0.f, 0.f, 0.f, 0.f};
    #pragma unroll
    for (int ks = 0; ks < 8; ++ks) {
      bf16x8 af = *(const bf16x8*)(&y2s[mt * 16 + l16][ks * 32 + quad * 8]);
      bf16x8 bf = *(const bf16x8*)(outWt + (size_t)(wave * 16 + l16) * DI + ks * 32 + quad * 8);
      acc = __builtin_amdgcn_mfma_f32_16x16x32_bf16(af, bf, acc, 0, 0, 0);
    }
    int col = wave * 16 + l16;
    size_t rb = rowbase + mt * 16 + quad * 4;
    #pragma unroll
    for (int r = 0; r < 4; ++r)
      out[(rb + r) * DM + col] = acc[r] + x[(rb + r) * DM + col];
  }
}

extern "C" void kernel_launch(void* const* d_in, const int* in_sizes, int n_in,
                              void* d_out, int out_size, void* d_ws, size_t ws_size,
                              hipStream_t stream) {
  const float* x      = (const float*)d_in[0];
  const float* norm_w = (const float*)d_in[1];
  const float* inW    = (const float*)d_in[2];
  const float* convw  = (const float*)d_in[3];
  const float* convb  = (const float*)d_in[4];
  const float* xprojw = (const float*)d_in[5];
  const float* dtw    = (const float*)d_in[6];
  const float* dtb    = (const float*)d_in[7];
  const float* alog   = (const float*)d_in[8];
  const float* Dp     = (const float*)d_in[9];
  const float* outw   = (const float*)d_in[10];
  float* out = (float*)d_out;

  const size_t CS = (size_t)B_ * NC * DI * DS;  // 2,097,152
  float2* PS    = (float2*)d_ws;                 // CS float2 (16 MB)
  float* sinit  = (float*)(PS + CS);             // CS floats (8 MB)
  ushort_t* bfbase = (ushort_t*)(sinit + CS);
  ushort_t* xbf    = bfbase;                        // M_*128
  ushort_t* xcbf   = xbf + (size_t)M_ * DM;         // M_*256
  ushort_t* resbf  = xcbf + (size_t)M_ * DI;        // M_*256
  ushort_t* deltab = resbf + (size_t)M_ * DI;       // M_*256
  ushort_t* Bmb    = deltab + (size_t)M_ * DI;      // M_*16
  ushort_t* Cmb    = Bmb + (size_t)M_ * DS;         // M_*16
  ushort_t* inWt   = Cmb + (size_t)M_ * DS;         // 512*128
  ushort_t* WbigT  = inWt + 512 * 128;              // 288*256
  ushort_t* outWt  = WbigT + NB * DI;               // 128*256

  prep_rms_kernel<<<M_ / 4 + (PREP_N + 255) / 256, 256, 0, stream>>>(
      x, norm_w, inW, xprojw, dtw, outw, xbf, inWt, WbigT, outWt);
  g1_conv_kernel<<<dim3(M_ / 128, 4), 256, 0, stream>>>(
      xbf, inWt, convw, convb, xcbf, resbf);
  scanA_kernel<<<B_ * NC, 512, 0, stream>>>(
      xcbf, WbigT, dtb, alog, deltab, Bmb, Cmb, PS);
  scanB_kernel<<<(B_ * DI * DS) / 64, 64, 0, stream>>>(PS, sinit);
  scanC_kernel<<<B_ * NC, 512, 0, stream>>>(
      deltab, xcbf, Bmb, Cmb, alog, Dp, resbf, sinit, outWt, x, out);
}